// Round 3
// baseline (198.269 us; speedup 1.0000x reference)
//
#include <hip/hip_runtime.h>
#include <hip/hip_bf16.h>
#include <stdint.h>

// B=8, N=1024, D=1024.  out = relu(adj @ (y@W) / adj_sumrow + b + x)
// R6: quad-buffered LDS pipeline (128KB), 3-ahead prefetch with counted
// vmcnt(12) -> ~768cy of latency slack (R4/R5 showed occupancy is not the
// limit; prefetch depth is). 512 threads, 128x128xBK64 tile, 1 block/CU.
// XCD-aware swizzle: gemm2 packs one batch per XCD L2, gemm1 one n-range.

typedef float  f32x4  __attribute__((ext_vector_type(4)));
typedef __bf16 bf16x8 __attribute__((ext_vector_type(8)));

__device__ __forceinline__ unsigned short f2bf(float f) {
  union { float f; unsigned int u; } c; c.f = f;
  unsigned int u = c.u;
  u += 0x7FFFu + ((u >> 16) & 1u);   // RNE; inputs finite
  return (unsigned short)(u >> 16);
}

__device__ __forceinline__ void async_cp16(const void* g, void* l) {
  __builtin_amdgcn_global_load_lds(
      (const __attribute__((address_space(1))) unsigned int*)g,
      (__attribute__((address_space(3))) unsigned int*)l, 16, 0, 0);
}

__device__ __forceinline__ void bar() { asm volatile("s_barrier" ::: "memory"); }

// ---------------- fused pre-pass (unchanged) ----------------

__global__ __launch_bounds__(256) void k_prep(
    const float4* __restrict__ y4, const float4* __restrict__ a4,
    ushort4* __restrict__ yb, ushort4* __restrict__ ab,
    const float* __restrict__ W, unsigned short* __restrict__ Wt)
{
  __shared__ float t[64][65];
  const int bid = blockIdx.x;
  if (bid < 16384) {
    const int i = bid * 256 + threadIdx.x;
    const bool isY = i < 2097152;
    const float4 v = isY ? y4[i] : a4[i - 2097152];
    ushort4 p;
    p.x = f2bf(v.x); p.y = f2bf(v.y); p.z = f2bf(v.z); p.w = f2bf(v.w);
    if (isY) yb[i] = p; else ab[i - 2097152] = p;
  } else {
    const int id = bid - 16384;
    const int n0 = (id & 15) * 64, k0 = (id >> 4) * 64;
    const int tx = threadIdx.x & 63, ty = threadIdx.x >> 6;
#pragma unroll
    for (int r = ty; r < 64; r += 4)
      t[r][tx] = W[(size_t)(k0 + r) * 1024 + n0 + tx];
    __syncthreads();
#pragma unroll
    for (int r = ty; r < 64; r += 4)
      Wt[(size_t)(n0 + r) * 1024 + k0 + tx] = f2bf(t[tx][r]);
  }
}

// ---------------- GEMM pieces: 128x128 tile, BK=64, 8 waves ----------------
// LDS row = 128B = 8 chunks of 16B; physical chunk = (logical + row) & 7.
// Staging applies inverse permutation on the global column (free).
// 512 threads: per stage each thread issues 2 A-loads + 2 B-loads = 4.

__device__ __forceinline__ void stage512(
    const unsigned short* __restrict__ A,  int sA,
    const unsigned short* __restrict__ Bt, int sB,
    int m0, int n0, int k0,
    unsigned short* la, unsigned short* lb,
    int wave, int rg, int colo)
{
#pragma unroll
  for (int s = 0; s < 2; ++s) {
    const int t = wave * 2 + s;                  // wave-uniform granule-group id
    async_cp16(A  + (size_t)(m0 + t * 8 + rg) * sA + k0 + colo, la + t * 512);
    async_cp16(Bt + (size_t)(n0 + t * 8 + rg) * sB + k0 + colo, lb + t * 512);
  }
}

// Per-wave output 32x64: waves 4M x 2N. acc[2][4]. 16 MFMA per K-tile.
__device__ __forceinline__ void compute512(
    const unsigned short* la, const unsigned short* lb,
    f32x4 acc[2][4], int wm, int wn, int quad, int l16)
{
#pragma unroll
  for (int h = 0; h < 2; ++h) {
    bf16x8 af[2], bfr[4];
#pragma unroll
    for (int i = 0; i < 2; ++i) {
      const int r = wm + i * 16 + l16;
      af[i] = *(const bf16x8*)(la + r * 64 + ((h * 4 + quad + r) & 7) * 8);
    }
#pragma unroll
    for (int j = 0; j < 4; ++j) {
      const int r = wn + j * 16 + l16;
      bfr[j] = *(const bf16x8*)(lb + r * 64 + ((h * 4 + quad + r) & 7) * 8);
    }
#pragma unroll
    for (int i = 0; i < 2; ++i)
#pragma unroll
      for (int j = 0; j < 4; ++j)
        acc[i][j] = __builtin_amdgcn_mfma_f32_16x16x32_bf16(af[i], bfr[j], acc[i][j], 0, 0, 0);
  }
}

// Quad-buffered mainloop, 3-ahead prefetch.
// Outstanding after issuing stage k+3: 16 loads; vmcnt(12) drains stage k only.
// Buffer for stage k+4 == buffer for stage k -> the post-compute barrier
// protects it before the next iteration's stage overwrites.
__device__ __forceinline__ void gemm_quad(
    const unsigned short* __restrict__ A,  int sA,
    const unsigned short* __restrict__ Bt, int sB,
    int m0, int n0, f32x4 acc[2][4], unsigned short* lsm, int tid)
{
  const int lane = tid & 63, wave = tid >> 6;
  const int wm = (wave >> 1) * 32, wn = (wave & 1) * 64;
  const int quad = lane >> 4, l16 = lane & 15;
  const int rg = lane >> 3;
  const int colo = (((lane & 7) - rg) & 7) * 8;    // inverse-swizzled k-offset

  stage512(A, sA, Bt, sB, m0, n0, 0,   lsm,           lsm + 8192,          wave, rg, colo);
  stage512(A, sA, Bt, sB, m0, n0, 64,  lsm + 16384,   lsm + 16384 + 8192,  wave, rg, colo);
  stage512(A, sA, Bt, sB, m0, n0, 128, lsm + 32768,   lsm + 32768 + 8192,  wave, rg, colo);

#pragma unroll
  for (int k = 0; k < 16; ++k) {
    if (k < 13) {
      unsigned short* base = lsm + ((k + 3) & 3) * 16384;
      stage512(A, sA, Bt, sB, m0, n0, (k + 3) * 64, base, base + 8192, wave, rg, colo);
      asm volatile("s_waitcnt vmcnt(12)" ::: "memory");
    } else if (k == 13) {
      asm volatile("s_waitcnt vmcnt(8)" ::: "memory");
    } else if (k == 14) {
      asm volatile("s_waitcnt vmcnt(4)" ::: "memory");
    } else {
      asm volatile("s_waitcnt vmcnt(0)" ::: "memory");
    }
    bar();
    const unsigned short* cb = lsm + (k & 3) * 16384;
    compute512(cb, cb + 8192, acc, wm, wn, quad, l16);
    bar();
  }
}

__device__ __forceinline__ void zero_acc(f32x4 acc[2][4]) {
#pragma unroll
  for (int i = 0; i < 2; ++i)
#pragma unroll
    for (int j = 0; j < 4; ++j)
#pragma unroll
      for (int r = 0; r < 4; ++r) acc[i][j][r] = 0.0f;
}

// ---------------- GEMM1: Sup2[d][b*1024+n] = (y@W)^T ----------------
// 1-D grid 512; XCD swizzle so each XCD owns one n-range:
// logical l = (bid%8)*64 + bid/8 ; m = l&7, n_tile = l>>3.
// XCD working set: Wt (2MB) + ybf n-slice (2MB) = 4MB = one L2.

__global__ __launch_bounds__(512, 2) void k_gemm1(
    const unsigned short* __restrict__ Wt,    // [1024][1024]
    const unsigned short* __restrict__ Ybf,   // [8192][1024]
    unsigned short* __restrict__ Sup2)        // [1024][8192]
{
  __shared__ __align__(16) unsigned short lsm[65536];  // 128 KB
  const int tid = threadIdx.x;
  const int bid = blockIdx.x;
  const int l = ((bid & 7) << 6) | (bid >> 3);
  const int m0 = (l & 7) << 7, n0 = (l >> 3) << 7;

  f32x4 acc[2][4];
  zero_acc(acc);
  gemm_quad(Wt, 1024, Ybf, 1024, m0, n0, acc, lsm, tid);

  const int lane = tid & 63, wave = tid >> 6;
  const int wm = (wave >> 1) * 32, wn = (wave & 1) * 64;
  const int quad = lane >> 4, l16 = lane & 15;
#pragma unroll
  for (int i = 0; i < 2; ++i) {
    const int mb = m0 + wm + i * 16 + quad * 4;
#pragma unroll
    for (int r = 0; r < 4; ++r) {
      unsigned short* row = Sup2 + ((size_t)(mb + r) << 13);
#pragma unroll
      for (int j = 0; j < 4; ++j)
        row[n0 + wn + j * 16 + l16] = f2bf(acc[i][j][r]);
    }
  }
}

// ------- GEMM2: out = relu(adj@support / rowsum + bias + x) -------
// 1-D grid 512; XCD swizzle so each XCD owns one batch:
// logical l = (bid%8)*64 + bid/8 ; b = l>>6, m = (l>>3)&7, n = l&7.
// XCD working set: adjbf[b] (2MB) + sup2 b-slice (2MB) = 4MB = one L2.

__global__ __launch_bounds__(512, 2) void k_gemm2(
    const unsigned short* __restrict__ AdjBf, // [8][1024][1024]
    const unsigned short* __restrict__ Sup2,  // [1024][8192]
    const float* __restrict__ x,
    const float* __restrict__ sumrow,         // [8][1024]
    const float* __restrict__ bias,           // [1024]
    float* __restrict__ out)
{
  __shared__ __align__(16) unsigned short lsm[65536];  // 128 KB
  const int tid = threadIdx.x;
  const int bid = blockIdx.x;
  const int l = ((bid & 7) << 6) | (bid >> 3);
  const int b = l >> 6;
  const int m0 = ((l >> 3) & 7) << 7, n0 = (l & 7) << 7;

  f32x4 acc[2][4];
  zero_acc(acc);
  gemm_quad(AdjBf + ((size_t)b << 20), 1024,
            Sup2 + ((size_t)b << 10), 8192,
            m0, n0, acc, lsm, tid);

  const float* xb = x   + ((size_t)b << 20);
  float*       ob = out + ((size_t)b << 20);
  const float* sr = sumrow + ((size_t)b << 10);
  const int lane = tid & 63, wave = tid >> 6;
  const int wm = (wave >> 1) * 32, wn = (wave & 1) * 64;
  const int quad = lane >> 4, l16 = lane & 15;

  float bv[4];
#pragma unroll
  for (int j = 0; j < 4; ++j) bv[j] = bias[n0 + wn + j * 16 + l16];

#pragma unroll
  for (int i = 0; i < 2; ++i) {
    const int mb = m0 + wm + i * 16 + quad * 4;
#pragma unroll
    for (int r = 0; r < 4; ++r) {
      const int m = mb + r;
      const float inv = 1.0f / sr[m];
#pragma unroll
      for (int j = 0; j < 4; ++j) {
        const int n = n0 + wn + j * 16 + l16;
        const size_t idx = (((size_t)m) << 10) + n;
        float v = acc[i][j][r] * inv + bv[j] + xb[idx];
        ob[idx] = fmaxf(v, 0.0f);
      }
    }
  }
}

// ---------------- launcher ----------------

extern "C" void kernel_launch(void* const* d_in, const int* in_sizes, int n_in,
                              void* d_out, int out_size, void* d_ws, size_t ws_size,
                              hipStream_t stream) {
  const float* x      = (const float*)d_in[0];
  const float* y      = (const float*)d_in[1];
  const float* adj    = (const float*)d_in[2];
  const float* sumrow = (const float*)d_in[3];
  const float* W      = (const float*)d_in[4];
  const float* bias   = (const float*)d_in[5];
  float* out = (float*)d_out;

  char* ws = (char*)d_ws;
  unsigned short* ybf   = (unsigned short*)(ws);                       // 16 MB
  unsigned short* adjbf = (unsigned short*)(ws + ((size_t)16 << 20));  // 16 MB
  unsigned short* wt    = (unsigned short*)(ws + ((size_t)32 << 20));  //  2 MB
  unsigned short* sup2  = (unsigned short*)(ws + ((size_t)34 << 20));  // 16 MB

  k_prep<<<dim3(16640), dim3(256), 0, stream>>>(
      (const float4*)y, (const float4*)adj, (ushort4*)ybf, (ushort4*)adjbf, W, wt);
  k_gemm1<<<dim3(512), dim3(512), 0, stream>>>(wt, ybf, sup2);
  k_gemm2<<<dim3(512), dim3(512), 0, stream>>>(adjbf, sup2, x, sumrow, bias, out);
}